// Round 5
// baseline (314.058 us; speedup 1.0000x reference)
//
#include <hip/hip_runtime.h>
#include <hip/hip_bf16.h>

#define DD 8
#define CC 512
#define NN 4096

typedef __bf16 bf16x8 __attribute__((ext_vector_type(8)));
typedef float  f32x4  __attribute__((ext_vector_type(4)));
typedef ushort ush8   __attribute__((ext_vector_type(8)));

__device__ __forceinline__ ushort f2bf(float f) {
  unsigned u = __float_as_uint(f);
  u = (u + 0x7fffu + ((u >> 16) & 1u)) >> 16;   // RNE
  return (ushort)u;
}
__device__ __forceinline__ float bf2f(ushort h) {
  return __uint_as_float(((unsigned)h) << 16);
}

__device__ __forceinline__ void gl_lds16(const ushort* g, ushort* l) {
  __builtin_amdgcn_global_load_lds(
      (const __attribute__((address_space(1))) void*)g,
      (__attribute__((address_space(3))) void*)l, 16, 0, 0);
}

// LDS chunk swizzle (T2, rule #21): slot (r, c) holds global chunk
// c ^ ((r>>1)&3); reads XOR the same term. Bank conflicts measured 0.

// ---------------------------------------------------------------------------
// K0: x fp32 -> q_hi, q_lo (bf16, [d][c][n]) and qT_hi (bf16, [d][n][c]).
//     v2: also zero-fills the single-Ep accumulator (2 floats/thread).
// ---------------------------------------------------------------------------
__global__ __launch_bounds__(256) void k0_convert(
    const float* __restrict__ x, ushort* __restrict__ qh,
    ushort* __restrict__ ql, ushort* __restrict__ qt,
    float* __restrict__ Ep) {
  int d = blockIdx.z, ct = blockIdx.y, nt = blockIdx.x;
  __shared__ ushort T[64][68];
  int t = threadIdx.x;
  // zero Ep: grid is 64*8*8*256 threads * 2 floats = 512*512*8 exactly
  size_t fid = ((((size_t)blockIdx.z * 8 + blockIdx.y) * 64 + blockIdx.x) * 256 + t) * 2;
  *(float2*)(Ep + fid) = make_float2(0.f, 0.f);

  int rr = t >> 4;           // 0..15
  int c4 = (t & 15) * 4;     // 0..60
  const float* xb = x + ((size_t)(d * CC + ct * 64)) * NN + nt * 64;
#pragma unroll
  for (int it = 0; it < 4; ++it) {
    int r = it * 16 + rr;
    float4 v = *(const float4*)(xb + (size_t)r * NN + c4);
    ushort h0 = f2bf(v.x), h1 = f2bf(v.y), h2 = f2bf(v.z), h3 = f2bf(v.w);
    ushort l0 = f2bf(v.x - bf2f(h0)), l1 = f2bf(v.y - bf2f(h1));
    ushort l2 = f2bf(v.z - bf2f(h2)), l3 = f2bf(v.w - bf2f(h3));
    size_t qi = ((size_t)(d * CC + ct * 64 + r)) * NN + nt * 64 + c4;
    *(ushort4*)(qh + qi) = make_ushort4(h0, h1, h2, h3);
    *(ushort4*)(ql + qi) = make_ushort4(l0, l1, l2, l3);
    *(ushort4*)&T[r][c4] = make_ushort4(h0, h1, h2, h3);
  }
  __syncthreads();
#pragma unroll
  for (int it = 0; it < 4; ++it) {
    int nl = it * 16 + rr;
    ushort4 v = make_ushort4(T[c4 + 0][nl], T[c4 + 1][nl], T[c4 + 2][nl], T[c4 + 3][nl]);
    *(ushort4*)(qt + ((size_t)(d * NN + nt * 64 + nl)) * CC + ct * 64 + c4) = v;
  }
}

// ---------------------------------------------------------------------------
// K1: Gram, upper-triangle tiles + symmetric mirror. 2-stage counted-vmcnt
//     staging pipeline (unchanged from v2). v3: split-K partials are
//     accumulated into a SINGLE 8.4 MB Ep via device-scope f32 atomicAdd
//     (L2/L3-resident) instead of ns separate 8.4 MB partial buffers —
//     kills the 64 MB write + 64 MB read Ep round-trip.
// ---------------------------------------------------------------------------
#define K1_STAGE(S)                                                            \
  {                                                                            \
    ushort* ls = lbase + ((S) & 1) * 8192;                                     \
    const ushort* gs = gsrc + (size_t)(S) * 32;                                \
    _Pragma("unroll")                                                          \
    for (int c = 0; c < 8; ++c)                                                \
      gl_lds16(gs + (size_t)c * 16 * NN, ls + c * 512);                        \
  }

#define K1_COMPUTE(SOFF)                                                       \
  {                                                                            \
    bf16x8 ah[4], al[4];                                                       \
    _Pragma("unroll")                                                          \
    for (int mi = 0; mi < 4; ++mi) {                                           \
      int off = (SOFF) + (wm + mi * 16 + fr) * 32 + qo;                        \
      ah[mi] = *(const bf16x8*)&As[off];                                       \
      al[mi] = *(const bf16x8*)&As[off + 4096];                                \
    }                                                                          \
    _Pragma("unroll")                                                          \
    for (int ni = 0; ni < 4; ++ni) {                                           \
      int off = (SOFF) + (wn + ni * 16 + fr) * 32 + qo;                        \
      bf16x8 bh = *(const bf16x8*)&Bs[off];                                    \
      bf16x8 bl = *(const bf16x8*)&Bs[off + 4096];                             \
      _Pragma("unroll")                                                        \
      for (int mi = 0; mi < 4; ++mi) {                                         \
        acc[mi][ni] = __builtin_amdgcn_mfma_f32_16x16x32_bf16(ah[mi], bh, acc[mi][ni], 0, 0, 0); \
        acc[mi][ni] = __builtin_amdgcn_mfma_f32_16x16x32_bf16(ah[mi], bl, acc[mi][ni], 0, 0, 0); \
        acc[mi][ni] = __builtin_amdgcn_mfma_f32_16x16x32_bf16(al[mi], bh, acc[mi][ni], 0, 0, 0); \
      }                                                                        \
    }                                                                          \
  }

__global__ __launch_bounds__(256, 2) void k1_gram(
    const ushort* __restrict__ qh, const ushort* __restrict__ ql,
    float* __restrict__ Ep, int ns, int nkk, int ksp) {
  __shared__ ushort As[2 * 2 * 4096];   // [stage][hi/lo][128*32]
  __shared__ ushort Bs[2 * 2 * 4096];
  int b = blockIdx.x;
  int s = b % ns;
  int rem = b / ns;
  int tile = rem % 10, d = rem / 10;
  // triangle tile lookup (nibble-packed): tm = row-tile, tn = col-tile, tm<=tn
  int tm = (int)((0x3221110000ULL >> (tile * 4)) & 15ULL);
  int tn = (int)((0x3323213210ULL >> (tile * 4)) & 15ULL);
  int t = threadIdx.x, lane = t & 63, w = t >> 6;
  int wm = (w >> 1) * 64, wn = (w & 1) * 64;
  int qd = lane >> 4, fr = lane & 15;
  int qo = (qd ^ ((fr >> 1) & 3)) * 8;                    // swizzled read chunk
  int so = ((lane & 3) ^ ((lane >> 3) & 3)) * 8;          // swizzled src chunk

  // wave w stages: 0->As_hi 1->As_lo 2->Bs_hi 3->Bs_lo
  const ushort* srcbase = (w & 1) ? ql : qh;
  int rowblk = (w < 2) ? tm : tn;
  const ushort* gsrc = srcbase +
      ((size_t)(d * CC + rowblk * 128 + (lane >> 2))) * NN +
      (size_t)s * ksp + so;
  ushort* lbase = ((w < 2) ? As : Bs) + (w & 1) * 4096;

  f32x4 acc[4][4];
#pragma unroll
  for (int i = 0; i < 4; ++i)
#pragma unroll
    for (int j = 0; j < 4; ++j) acc[i][j] = (f32x4){0.f, 0.f, 0.f, 0.f};

  // prologue: stage 0
  K1_STAGE(0)

#pragma unroll 1
  for (int kk = 0; kk < nkk - 1; ++kk) {
    // overwrite guard: all waves' ds_reads of buf[(kk+1)&1] retired
    asm volatile("s_waitcnt lgkmcnt(0)\n\ts_barrier" ::: "memory");
    K1_STAGE(kk + 1)
    // stage kk ready on all waves; kk+1's 8 loads remain in flight
    asm volatile("s_waitcnt vmcnt(8)\n\ts_barrier" ::: "memory");
    K1_COMPUTE((kk & 1) * 8192)
  }
  // tail: last stage, full drain (no overwrite hazard)
  asm volatile("s_waitcnt vmcnt(0) lgkmcnt(0)\n\ts_barrier" ::: "memory");
  K1_COMPUTE(((nkk - 1) & 1) * 8192)

  size_t ebase = (size_t)d * ((size_t)CC * CC);
  // normal accumulate (tile tm,tn): scalar strided atomics
#pragma unroll
  for (int mi = 0; mi < 4; ++mi) {
    int r0 = tm * 128 + wm + mi * 16 + qd * 4;
#pragma unroll
    for (int ni = 0; ni < 4; ++ni) {
      int c0 = tn * 128 + wn + ni * 16 + fr;
      float* ep = Ep + ebase + (size_t)r0 * CC + c0;
#pragma unroll
      for (int r = 0; r < 4; ++r) atomicAdd(ep + (size_t)r * CC, acc[mi][ni][r]);
    }
  }
  // mirror accumulate (tile tn,tm) = transpose: 4 consecutive atomics/lane
  if (tm != tn) {
#pragma unroll
    for (int mi = 0; mi < 4; ++mi) {
      int r0 = tm * 128 + wm + mi * 16 + qd * 4;
#pragma unroll
      for (int ni = 0; ni < 4; ++ni) {
        int c0 = tn * 128 + wn + ni * 16 + fr;
        float* mp = Ep + ebase + (size_t)c0 * CC + r0;
        atomicAdd(mp + 0, acc[mi][ni][0]);
        atomicAdd(mp + 1, acc[mi][ni][1]);
        atomicAdd(mp + 2, acc[mi][ni][2]);
        atomicAdd(mp + 3, acc[mi][ni][3]);
      }
    }
  }
}

// ---------------------------------------------------------------------------
// K2: wave-per-row double softmax + transposed bf16 write via LDS.
//     v2: reads the single pre-summed Ep (8.4 MB, L2/L3-hot) — no split loop.
// ---------------------------------------------------------------------------
__device__ __forceinline__ float wmin(float v) {
#pragma unroll
  for (int o = 32; o > 0; o >>= 1) v = fminf(v, __shfl_xor(v, o));
  return v;
}
__device__ __forceinline__ float wmax(float v) {
#pragma unroll
  for (int o = 32; o > 0; o >>= 1) v = fmaxf(v, __shfl_xor(v, o));
  return v;
}
__device__ __forceinline__ float wsum(float v) {
#pragma unroll
  for (int o = 32; o > 0; o >>= 1) v += __shfl_xor(v, o);
  return v;
}

__global__ __launch_bounds__(256) void k2_softmax(
    const float* __restrict__ Ep, const float* __restrict__ atten,
    ushort* __restrict__ a2t) {
  int d = blockIdx.y, i0 = blockIdx.x * 8;
  int t = threadIdx.x, lane = t & 63, w = t >> 6;
  int j8 = lane * 8;
  __shared__ ushort T[8][520];

#pragma unroll
  for (int r2 = 0; r2 < 2; ++r2) {
    int ri = w * 2 + r2;
    size_t base = ((size_t)(d * CC + i0 + ri)) * CC + j8;
    const float* p = Ep + base;
    f32x4 a0 = *(const f32x4*)p;
    f32x4 a1 = *(const f32x4*)(p + 4);
    float mn = fminf(fminf(fminf(a0[0], a0[1]), fminf(a0[2], a0[3])),
                     fminf(fminf(a1[0], a1[1]), fminf(a1[2], a1[3])));
    mn = wmin(mn);
    float p0 = __expf(mn - a0[0]), p1 = __expf(mn - a0[1]);
    float p2 = __expf(mn - a0[2]), p3 = __expf(mn - a0[3]);
    float p4 = __expf(mn - a1[0]), p5 = __expf(mn - a1[1]);
    float p6 = __expf(mn - a1[2]), p7 = __expf(mn - a1[3]);
    float s1 = wsum(p0 + p1 + p2 + p3 + p4 + p5 + p6 + p7);
    float inv1 = 1.0f / s1;
    const float* ap = atten + base;
    f32x4 t0 = *(const f32x4*)ap;
    f32x4 t1 = *(const f32x4*)(ap + 4);
    float u0 = p0 * inv1 + t0[0], u1 = p1 * inv1 + t0[1];
    float u2 = p2 * inv1 + t0[2], u3 = p3 * inv1 + t0[3];
    float u4 = p4 * inv1 + t1[0], u5 = p5 * inv1 + t1[1];
    float u6 = p6 * inv1 + t1[2], u7 = p7 * inv1 + t1[3];
    float mx = wmax(fmaxf(fmaxf(fmaxf(u0, u1), fmaxf(u2, u3)),
                          fmaxf(fmaxf(u4, u5), fmaxf(u6, u7))));
    float q0 = __expf(u0 - mx), q1 = __expf(u1 - mx);
    float q2 = __expf(u2 - mx), q3 = __expf(u3 - mx);
    float q4 = __expf(u4 - mx), q5 = __expf(u5 - mx);
    float q6 = __expf(u6 - mx), q7 = __expf(u7 - mx);
    float s2 = wsum(q0 + q1 + q2 + q3 + q4 + q5 + q6 + q7);
    float inv2 = 1.0f / s2;
    ush8 o;
    o[0] = f2bf(q0 * inv2); o[1] = f2bf(q1 * inv2);
    o[2] = f2bf(q2 * inv2); o[3] = f2bf(q3 * inv2);
    o[4] = f2bf(q4 * inv2); o[5] = f2bf(q5 * inv2);
    o[6] = f2bf(q6 * inv2); o[7] = f2bf(q7 * inv2);
    *(ush8*)&T[ri][j8] = o;
  }
  __syncthreads();
  // write att2^T: a2t[d][j][i0..i0+7], coalesced 16B per thread
#pragma unroll
  for (int it = 0; it < 2; ++it) {
    int j = t + it * 256;
    ush8 o;
#pragma unroll
    for (int k = 0; k < 8; ++k) o[k] = T[k][j];
    *(ush8*)&a2t[((size_t)(d * CC + j)) * CC + i0] = o;
  }
}

// ---------------------------------------------------------------------------
// K3: out[d][j][n] = gamma * sum_i att2T[d][j][i] * qT[d][n][i] + x[d][j][n]
//     4-stage counted-vmcnt pipeline, split into two d-half dispatches
//     (512 blocks each) for profiler visibility. Unchanged this round.
// ---------------------------------------------------------------------------
#define K3_COMPUTE(SOFF)                                                       \
  {                                                                            \
    bf16x8 qf[4];                                                              \
    _Pragma("unroll")                                                          \
    for (int ii = 0; ii < 4; ++ii)                                             \
      qf[ii] = *(const bf16x8*)&Bs[(SOFF) + (wn2 + ii * 16 + fr) * 32 + qo];   \
    _Pragma("unroll")                                                          \
    for (int jj = 0; jj < 4; ++jj) {                                           \
      bf16x8 af = *(const bf16x8*)&As[(SOFF) + (wj + jj * 16 + fr) * 32 + qo]; \
      _Pragma("unroll")                                                        \
      for (int ii = 0; ii < 4; ++ii)                                           \
        acc[ii][jj] = __builtin_amdgcn_mfma_f32_16x16x32_bf16(                 \
            qf[ii], af, acc[ii][jj], 0, 0, 0);                                 \
    }                                                                          \
  }

#define K3_STAGE(S)                                                            \
  {                                                                            \
    ushort* ls = mylds + ((S) & 3) * 4096;                                     \
    const ushort* gs = g0 + (size_t)(S) * 32;                                  \
    _Pragma("unroll")                                                          \
    for (int c = 0; c < 4; ++c)                                                \
      gl_lds16(gs + (size_t)(c * 16) * CC, ls + c * 512);                      \
  }

__global__ __launch_bounds__(256, 2) void k3_out(
    const ushort* __restrict__ a2t, const ushort* __restrict__ qt,
    const float* __restrict__ x, const float* __restrict__ gamma,
    float* __restrict__ out, int d0) {
  __shared__ ushort As[4 * 128 * 32];   // a2t tiles, 4-stage circular
  __shared__ ushort Bs[4 * 128 * 32];   // qt tiles, 4-stage circular
  int b = blockIdx.x;
  int nt = b & 31, jt = (b >> 5) & 3, d = d0 + (b >> 7);
  int t = threadIdx.x, lane = t & 63, w = t >> 6;
  int wj = (w >> 1) * 64, wn2 = (w & 1) * 64;
  int qd = lane >> 4, fr = lane & 15;
  int qo = (qd ^ ((fr >> 1) & 3)) * 8;                    // swizzled read chunk
  int so = ((lane & 3) ^ ((lane >> 3) & 3)) * 8;          // swizzled src chunk

  const ushort* src = (w < 2)
      ? (a2t + (size_t)d * CC * CC + (size_t)(jt * 128) * CC)
      : (qt + (size_t)d * NN * CC + (size_t)(nt * 128) * CC);
  int cbase = (w & 1) * 4;   // w0: As rows 0-63, w1: As 64-127, w2/w3: Bs
  const ushort* g0 = src + ((size_t)(cbase * 16 + (lane >> 2))) * CC + so;
  ushort* mylds = ((w < 2) ? As : Bs) + cbase * 512;

  f32x4 acc[4][4];   // acc[ii(n)][jj(j)]
#pragma unroll
  for (int i = 0; i < 4; ++i)
#pragma unroll
    for (int j = 0; j < 4; ++j) acc[i][j] = (f32x4){0.f, 0.f, 0.f, 0.f};

  // prologue: issue stages 0,1,2 (12 loads/wave in flight)
  K3_STAGE(0)
  K3_STAGE(1)
  K3_STAGE(2)

  // steady state: 13 iters (kk=0..12), each issues stage kk+3 (3..15)
#pragma unroll 1
  for (int kk = 0; kk < 13; ++kk) {
    asm volatile("s_waitcnt vmcnt(8)\n\ts_barrier" ::: "memory");
    K3_STAGE(kk + 3)
    K3_COMPUTE((kk & 3) * 4096)
  }
  // tail: kk=13,14,15 — drain 8 -> 4 -> 0
  asm volatile("s_waitcnt vmcnt(8)\n\ts_barrier" ::: "memory");
  K3_COMPUTE(1 * 4096)
  asm volatile("s_waitcnt vmcnt(4)\n\ts_barrier" ::: "memory");
  K3_COMPUTE(2 * 4096)
  asm volatile("s_waitcnt vmcnt(0)\n\ts_barrier" ::: "memory");

  // prime x-prefetch for ii=0,1 (8 float4) so HBM latency hides under the
  // final 16 MFMAs, then compute last stage.
  int n0b = nt * 128 + wn2 + qd * 4;
  float4 xp0[4], xp1[4];
#pragma unroll
  for (int jj = 0; jj < 4; ++jj) {
    size_t rb = ((size_t)(d * CC + jt * 128 + wj + jj * 16 + fr)) * NN;
    xp0[jj] = *(const float4*)(x + rb + n0b);
    xp1[jj] = *(const float4*)(x + rb + n0b + 16);
  }
  K3_COMPUTE(3 * 4096)

  // epilogue: load-before-store rolling, 2 groups in flight.
  float g = gamma[0];
  float4 x2[4], x3[4];
#pragma unroll
  for (int jj = 0; jj < 4; ++jj)
    x2[jj] = *(const float4*)(x + ((size_t)(d * CC + jt * 128 + wj + jj * 16 + fr)) * NN + n0b + 32);
#pragma unroll
  for (int jj = 0; jj < 4; ++jj) {
    size_t idx = ((size_t)(d * CC + jt * 128 + wj + jj * 16 + fr)) * NN + n0b;
    *(float4*)(out + idx) = make_float4(g * acc[0][jj][0] + xp0[jj].x,
                                        g * acc[0][jj][1] + xp0[jj].y,
                                        g * acc[0][jj][2] + xp0[jj].z,
                                        g * acc[0][jj][3] + xp0[jj].w);
  }
#pragma unroll
  for (int jj = 0; jj < 4; ++jj)
    x3[jj] = *(const float4*)(x + ((size_t)(d * CC + jt * 128 + wj + jj * 16 + fr)) * NN + n0b + 48);
#pragma unroll
  for (int jj = 0; jj < 4; ++jj) {
    size_t idx = ((size_t)(d * CC + jt * 128 + wj + jj * 16 + fr)) * NN + n0b + 16;
    *(float4*)(out + idx) = make_float4(g * acc[1][jj][0] + xp1[jj].x,
                                        g * acc[1][jj][1] + xp1[jj].y,
                                        g * acc[1][jj][2] + xp1[jj].z,
                                        g * acc[1][jj][3] + xp1[jj].w);
  }
#pragma unroll
  for (int jj = 0; jj < 4; ++jj) {
    size_t idx = ((size_t)(d * CC + jt * 128 + wj + jj * 16 + fr)) * NN + n0b + 32;
    *(float4*)(out + idx) = make_float4(g * acc[2][jj][0] + x2[jj].x,
                                        g * acc[2][jj][1] + x2[jj].y,
                                        g * acc[2][jj][2] + x2[jj].z,
                                        g * acc[2][jj][3] + x2[jj].w);
  }
#pragma unroll
  for (int jj = 0; jj < 4; ++jj) {
    size_t idx = ((size_t)(d * CC + jt * 128 + wj + jj * 16 + fr)) * NN + n0b + 48;
    *(float4*)(out + idx) = make_float4(g * acc[3][jj][0] + x3[jj].x,
                                        g * acc[3][jj][1] + x3[jj].y,
                                        g * acc[3][jj][2] + x3[jj].z,
                                        g * acc[3][jj][3] + x3[jj].w);
  }
}

// ---------------------------------------------------------------------------
extern "C" void kernel_launch(void* const* d_in, const int* in_sizes, int n_in,
                              void* d_out, int out_size, void* d_ws, size_t ws_size,
                              hipStream_t stream) {
  (void)in_sizes; (void)n_in; (void)out_size; (void)ws_size;
  const float* x     = (const float*)d_in[0];
  const float* atten = (const float*)d_in[1];
  const float* gamma = (const float*)d_in[2];
  float* out = (float*)d_out;

  char* ws = (char*)d_ws;
  ushort* qh  = (ushort*)(ws);                    // 33554432 B
  ushort* ql  = (ushort*)(ws + 33554432);         // 33554432 B
  ushort* qt  = (ushort*)(ws + 67108864);         // 33554432 B
  ushort* a2t = (ushort*)(ws + 100663296);        // 4194304 B
  float*  Ep  = (float*) (ws + 104857600);        // 8388608 B (single acc)

  const int ns = 8;           // K-split count (grid sizing only now)
  const int ksp = NN / ns;    // 512
  const int nkk = ksp / 32;   // 16

  k0_convert<<<dim3(64, 8, 8), 256, 0, stream>>>(x, qh, ql, qt, Ep);
  k1_gram   <<<dim3(80 * ns), 256, 0, stream>>>(qh, ql, Ep, ns, nkk, ksp);
  k2_softmax<<<dim3(64, 8), 256, 0, stream>>>(Ep, atten, a2t);
  k3_out    <<<dim3(512), 256, 0, stream>>>(a2t, qt, x, gamma, out, 0);
  k3_out    <<<dim3(512), 256, 0, stream>>>(a2t, qt, x, gamma, out, 4);
}

// Round 6
// 228.831 us; speedup vs baseline: 1.3724x; 1.3724x over previous
//
#include <hip/hip_runtime.h>
#include <hip/hip_bf16.h>

#define DD 8
#define CC 512
#define NN 4096

typedef __bf16 bf16x8 __attribute__((ext_vector_type(8)));
typedef float  f32x4  __attribute__((ext_vector_type(4)));
typedef ushort ush8   __attribute__((ext_vector_type(8)));

__device__ __forceinline__ ushort f2bf(float f) {
  unsigned u = __float_as_uint(f);
  u = (u + 0x7fffu + ((u >> 16) & 1u)) >> 16;   // RNE
  return (ushort)u;
}
__device__ __forceinline__ float bf2f(ushort h) {
  return __uint_as_float(((unsigned)h) << 16);
}

__device__ __forceinline__ void gl_lds16(const ushort* g, ushort* l) {
  __builtin_amdgcn_global_load_lds(
      (const __attribute__((address_space(1))) void*)g,
      (__attribute__((address_space(3))) void*)l, 16, 0, 0);
}

// LDS chunk swizzle (T2, rule #21): slot (r, c) holds global chunk
// c ^ ((r>>1)&3); reads XOR the same term. Bank conflicts measured 0.

// ---------------------------------------------------------------------------
// K0: x fp32 -> q_hi, q_lo (bf16, [d][c][n]) and qT_hi (bf16, [d][n][c])
// ---------------------------------------------------------------------------
__global__ __launch_bounds__(256) void k0_convert(
    const float* __restrict__ x, ushort* __restrict__ qh,
    ushort* __restrict__ ql, ushort* __restrict__ qt) {
  int d = blockIdx.z, ct = blockIdx.y, nt = blockIdx.x;
  __shared__ ushort T[64][68];
  int t = threadIdx.x;
  int rr = t >> 4;           // 0..15
  int c4 = (t & 15) * 4;     // 0..60
  const float* xb = x + ((size_t)(d * CC + ct * 64)) * NN + nt * 64;
#pragma unroll
  for (int it = 0; it < 4; ++it) {
    int r = it * 16 + rr;
    float4 v = *(const float4*)(xb + (size_t)r * NN + c4);
    ushort h0 = f2bf(v.x), h1 = f2bf(v.y), h2 = f2bf(v.z), h3 = f2bf(v.w);
    ushort l0 = f2bf(v.x - bf2f(h0)), l1 = f2bf(v.y - bf2f(h1));
    ushort l2 = f2bf(v.z - bf2f(h2)), l3 = f2bf(v.w - bf2f(h3));
    size_t qi = ((size_t)(d * CC + ct * 64 + r)) * NN + nt * 64 + c4;
    *(ushort4*)(qh + qi) = make_ushort4(h0, h1, h2, h3);
    *(ushort4*)(ql + qi) = make_ushort4(l0, l1, l2, l3);
    *(ushort4*)&T[r][c4] = make_ushort4(h0, h1, h2, h3);
  }
  __syncthreads();
#pragma unroll
  for (int it = 0; it < 4; ++it) {
    int nl = it * 16 + rr;
    ushort4 v = make_ushort4(T[c4 + 0][nl], T[c4 + 1][nl], T[c4 + 2][nl], T[c4 + 3][nl]);
    *(ushort4*)(qt + ((size_t)(d * NN + nt * 64 + nl)) * CC + ct * 64 + c4) = v;
  }
}

// ---------------------------------------------------------------------------
// K1: Gram partials, upper-triangle tiles + symmetric mirror, split-K
//     partial stores (atomics reverted — r5: atomicAdd doubled write traffic,
//     44->135us). 2-stage counted-vmcnt staging pipeline. Note: s = b % ns
//     with ns=8 already XCD-pins each K-slice (dispatch round-robins b%8).
// ---------------------------------------------------------------------------
#define K1_STAGE(S)                                                            \
  {                                                                            \
    ushort* ls = lbase + ((S) & 1) * 8192;                                     \
    const ushort* gs = gsrc + (size_t)(S) * 32;                                \
    _Pragma("unroll")                                                          \
    for (int c = 0; c < 8; ++c)                                                \
      gl_lds16(gs + (size_t)c * 16 * NN, ls + c * 512);                        \
  }

#define K1_COMPUTE(SOFF)                                                       \
  {                                                                            \
    bf16x8 ah[4], al[4];                                                       \
    _Pragma("unroll")                                                          \
    for (int mi = 0; mi < 4; ++mi) {                                           \
      int off = (SOFF) + (wm + mi * 16 + fr) * 32 + qo;                        \
      ah[mi] = *(const bf16x8*)&As[off];                                       \
      al[mi] = *(const bf16x8*)&As[off + 4096];                                \
    }                                                                          \
    _Pragma("unroll")                                                          \
    for (int ni = 0; ni < 4; ++ni) {                                           \
      int off = (SOFF) + (wn + ni * 16 + fr) * 32 + qo;                        \
      bf16x8 bh = *(const bf16x8*)&Bs[off];                                    \
      bf16x8 bl = *(const bf16x8*)&Bs[off + 4096];                             \
      _Pragma("unroll")                                                        \
      for (int mi = 0; mi < 4; ++mi) {                                         \
        acc[mi][ni] = __builtin_amdgcn_mfma_f32_16x16x32_bf16(ah[mi], bh, acc[mi][ni], 0, 0, 0); \
        acc[mi][ni] = __builtin_amdgcn_mfma_f32_16x16x32_bf16(ah[mi], bl, acc[mi][ni], 0, 0, 0); \
        acc[mi][ni] = __builtin_amdgcn_mfma_f32_16x16x32_bf16(al[mi], bh, acc[mi][ni], 0, 0, 0); \
      }                                                                        \
    }                                                                          \
  }

__global__ __launch_bounds__(256, 2) void k1_gram(
    const ushort* __restrict__ qh, const ushort* __restrict__ ql,
    float* __restrict__ Ep, int ns, int nkk, int ksp) {
  __shared__ ushort As[2 * 2 * 4096];   // [stage][hi/lo][128*32]
  __shared__ ushort Bs[2 * 2 * 4096];
  int b = blockIdx.x;
  int s = b % ns;
  int rem = b / ns;
  int tile = rem % 10, d = rem / 10;
  // triangle tile lookup (nibble-packed): tm = row-tile, tn = col-tile, tm<=tn
  int tm = (int)((0x3221110000ULL >> (tile * 4)) & 15ULL);
  int tn = (int)((0x3323213210ULL >> (tile * 4)) & 15ULL);
  int t = threadIdx.x, lane = t & 63, w = t >> 6;
  int wm = (w >> 1) * 64, wn = (w & 1) * 64;
  int qd = lane >> 4, fr = lane & 15;
  int qo = (qd ^ ((fr >> 1) & 3)) * 8;                    // swizzled read chunk
  int so = ((lane & 3) ^ ((lane >> 3) & 3)) * 8;          // swizzled src chunk

  // wave w stages: 0->As_hi 1->As_lo 2->Bs_hi 3->Bs_lo
  const ushort* srcbase = (w & 1) ? ql : qh;
  int rowblk = (w < 2) ? tm : tn;
  const ushort* gsrc = srcbase +
      ((size_t)(d * CC + rowblk * 128 + (lane >> 2))) * NN +
      (size_t)s * ksp + so;
  ushort* lbase = ((w < 2) ? As : Bs) + (w & 1) * 4096;

  f32x4 acc[4][4];
#pragma unroll
  for (int i = 0; i < 4; ++i)
#pragma unroll
    for (int j = 0; j < 4; ++j) acc[i][j] = (f32x4){0.f, 0.f, 0.f, 0.f};

  // prologue: stage 0
  K1_STAGE(0)

#pragma unroll 1
  for (int kk = 0; kk < nkk - 1; ++kk) {
    // overwrite guard: all waves' ds_reads of buf[(kk+1)&1] retired
    asm volatile("s_waitcnt lgkmcnt(0)\n\ts_barrier" ::: "memory");
    K1_STAGE(kk + 1)
    // stage kk ready on all waves; kk+1's 8 loads remain in flight
    asm volatile("s_waitcnt vmcnt(8)\n\ts_barrier" ::: "memory");
    K1_COMPUTE((kk & 1) * 8192)
  }
  // tail: last stage, full drain (no overwrite hazard)
  asm volatile("s_waitcnt vmcnt(0) lgkmcnt(0)\n\ts_barrier" ::: "memory");
  K1_COMPUTE(((nkk - 1) & 1) * 8192)

  size_t ebase = ((size_t)(s * DD + d)) * ((size_t)CC * CC);
  // normal store (tile tm,tn): scalar strided
#pragma unroll
  for (int mi = 0; mi < 4; ++mi) {
    int r0 = tm * 128 + wm + mi * 16 + qd * 4;
#pragma unroll
    for (int ni = 0; ni < 4; ++ni) {
      int c0 = tn * 128 + wn + ni * 16 + fr;
      float* ep = Ep + ebase + (size_t)r0 * CC + c0;
#pragma unroll
      for (int r = 0; r < 4; ++r) ep[(size_t)r * CC] = acc[mi][ni][r];
    }
  }
  // mirror store (tile tn,tm) = transpose: per-lane float4 along rows
  if (tm != tn) {
#pragma unroll
    for (int mi = 0; mi < 4; ++mi) {
      int r0 = tm * 128 + wm + mi * 16 + qd * 4;
#pragma unroll
      for (int ni = 0; ni < 4; ++ni) {
        int c0 = tn * 128 + wn + ni * 16 + fr;
        float4 v = make_float4(acc[mi][ni][0], acc[mi][ni][1],
                               acc[mi][ni][2], acc[mi][ni][3]);
        *(float4*)(Ep + ebase + (size_t)c0 * CC + r0) = v;
      }
    }
  }
}

// ---------------------------------------------------------------------------
// K2: wave-per-row reduce + double softmax + transposed bf16 write via LDS.
//     v3: 1D grid with d = b&7 so each d's blocks land on one XCD (T1):
//     Ep[.][d] slices (8 MB) get XCD-L2 affinity.
// ---------------------------------------------------------------------------
__device__ __forceinline__ float wmin(float v) {
#pragma unroll
  for (int o = 32; o > 0; o >>= 1) v = fminf(v, __shfl_xor(v, o));
  return v;
}
__device__ __forceinline__ float wmax(float v) {
#pragma unroll
  for (int o = 32; o > 0; o >>= 1) v = fmaxf(v, __shfl_xor(v, o));
  return v;
}
__device__ __forceinline__ float wsum(float v) {
#pragma unroll
  for (int o = 32; o > 0; o >>= 1) v += __shfl_xor(v, o);
  return v;
}

__global__ __launch_bounds__(256) void k2_softmax(
    const float* __restrict__ Ep, const float* __restrict__ atten,
    ushort* __restrict__ a2t, int ns) {
  int d = blockIdx.x & 7;            // XCD-pinned
  int i0 = (blockIdx.x >> 3) * 8;
  int t = threadIdx.x, lane = t & 63, w = t >> 6;
  int j8 = lane * 8;
  __shared__ ushort T[8][520];
  const size_t SP = (size_t)DD * CC * CC;

#pragma unroll
  for (int r2 = 0; r2 < 2; ++r2) {
    int ri = w * 2 + r2;
    size_t base = ((size_t)(d * CC + i0 + ri)) * CC + j8;
    f32x4 a0 = (f32x4){0.f, 0.f, 0.f, 0.f};
    f32x4 a1 = (f32x4){0.f, 0.f, 0.f, 0.f};
    for (int s = 0; s < ns; ++s) {
      const float* p = Ep + (size_t)s * SP + base;
      a0 += *(const f32x4*)p;
      a1 += *(const f32x4*)(p + 4);
    }
    float mn = fminf(fminf(fminf(a0[0], a0[1]), fminf(a0[2], a0[3])),
                     fminf(fminf(a1[0], a1[1]), fminf(a1[2], a1[3])));
    mn = wmin(mn);
    float p0 = __expf(mn - a0[0]), p1 = __expf(mn - a0[1]);
    float p2 = __expf(mn - a0[2]), p3 = __expf(mn - a0[3]);
    float p4 = __expf(mn - a1[0]), p5 = __expf(mn - a1[1]);
    float p6 = __expf(mn - a1[2]), p7 = __expf(mn - a1[3]);
    float s1 = wsum(p0 + p1 + p2 + p3 + p4 + p5 + p6 + p7);
    float inv1 = 1.0f / s1;
    const float* ap = atten + base;
    f32x4 t0 = *(const f32x4*)ap;
    f32x4 t1 = *(const f32x4*)(ap + 4);
    float u0 = p0 * inv1 + t0[0], u1 = p1 * inv1 + t0[1];
    float u2 = p2 * inv1 + t0[2], u3 = p3 * inv1 + t0[3];
    float u4 = p4 * inv1 + t1[0], u5 = p5 * inv1 + t1[1];
    float u6 = p6 * inv1 + t1[2], u7 = p7 * inv1 + t1[3];
    float mx = wmax(fmaxf(fmaxf(fmaxf(u0, u1), fmaxf(u2, u3)),
                          fmaxf(fmaxf(u4, u5), fmaxf(u6, u7))));
    float q0 = __expf(u0 - mx), q1 = __expf(u1 - mx);
    float q2 = __expf(u2 - mx), q3 = __expf(u3 - mx);
    float q4 = __expf(u4 - mx), q5 = __expf(u5 - mx);
    float q6 = __expf(u6 - mx), q7 = __expf(u7 - mx);
    float s2 = wsum(q0 + q1 + q2 + q3 + q4 + q5 + q6 + q7);
    float inv2 = 1.0f / s2;
    ush8 o;
    o[0] = f2bf(q0 * inv2); o[1] = f2bf(q1 * inv2);
    o[2] = f2bf(q2 * inv2); o[3] = f2bf(q3 * inv2);
    o[4] = f2bf(q4 * inv2); o[5] = f2bf(q5 * inv2);
    o[6] = f2bf(q6 * inv2); o[7] = f2bf(q7 * inv2);
    *(ush8*)&T[ri][j8] = o;
  }
  __syncthreads();
  // write att2^T: a2t[d][j][i0..i0+7], coalesced 16B per thread
#pragma unroll
  for (int it = 0; it < 2; ++it) {
    int j = t + it * 256;
    ush8 o;
#pragma unroll
    for (int k = 0; k < 8; ++k) o[k] = T[k][j];
    *(ush8*)&a2t[((size_t)(d * CC + j)) * CC + i0] = o;
  }
}

// ---------------------------------------------------------------------------
// K3: out[d][j][n] = gamma * sum_i att2T[d][j][i] * qT[d][n][i] + x[d][j][n]
//     v6: single 1024-block dispatch again, with XCD-affine remap (T1):
//     d = b&7 pins all 128 blocks of a given d onto one XCD, whose working
//     set qt[d] (4MB) + a2t[d] (0.5MB) ~= one XCD L2, 7x intra-d reuse.
//     4-stage counted-vmcnt pipeline unchanged.
// ---------------------------------------------------------------------------
#define K3_COMPUTE(SOFF)                                                       \
  {                                                                            \
    bf16x8 qf[4];                                                              \
    _Pragma("unroll")                                                          \
    for (int ii = 0; ii < 4; ++ii)                                             \
      qf[ii] = *(const bf16x8*)&Bs[(SOFF) + (wn2 + ii * 16 + fr) * 32 + qo];   \
    _Pragma("unroll")                                                          \
    for (int jj = 0; jj < 4; ++jj) {                                           \
      bf16x8 af = *(const bf16x8*)&As[(SOFF) + (wj + jj * 16 + fr) * 32 + qo]; \
      _Pragma("unroll")                                                        \
      for (int ii = 0; ii < 4; ++ii)                                           \
        acc[ii][jj] = __builtin_amdgcn_mfma_f32_16x16x32_bf16(                 \
            qf[ii], af, acc[ii][jj], 0, 0, 0);                                 \
    }                                                                          \
  }

#define K3_STAGE(S)                                                            \
  {                                                                            \
    ushort* ls = mylds + ((S) & 3) * 4096;                                     \
    const ushort* gs = g0 + (size_t)(S) * 32;                                  \
    _Pragma("unroll")                                                          \
    for (int c = 0; c < 4; ++c)                                                \
      gl_lds16(gs + (size_t)(c * 16) * CC, ls + c * 512);                      \
  }

__global__ __launch_bounds__(256, 2) void k3_out(
    const ushort* __restrict__ a2t, const ushort* __restrict__ qt,
    const float* __restrict__ x, const float* __restrict__ gamma,
    float* __restrict__ out) {
  __shared__ ushort As[4 * 128 * 32];   // a2t tiles, 4-stage circular
  __shared__ ushort Bs[4 * 128 * 32];   // qt tiles, 4-stage circular
  int b = blockIdx.x;
  int d = b & 7;                         // XCD-pinned (b%8 -> XCD round-robin)
  int nt = (b >> 3) & 31, jt = b >> 8;   // bijective: b = jt*256 + nt*8 + d
  int t = threadIdx.x, lane = t & 63, w = t >> 6;
  int wj = (w >> 1) * 64, wn2 = (w & 1) * 64;
  int qd = lane >> 4, fr = lane & 15;
  int qo = (qd ^ ((fr >> 1) & 3)) * 8;                    // swizzled read chunk
  int so = ((lane & 3) ^ ((lane >> 3) & 3)) * 8;          // swizzled src chunk

  const ushort* src = (w < 2)
      ? (a2t + (size_t)d * CC * CC + (size_t)(jt * 128) * CC)
      : (qt + (size_t)d * NN * CC + (size_t)(nt * 128) * CC);
  int cbase = (w & 1) * 4;   // w0: As rows 0-63, w1: As 64-127, w2/w3: Bs
  const ushort* g0 = src + ((size_t)(cbase * 16 + (lane >> 2))) * CC + so;
  ushort* mylds = ((w < 2) ? As : Bs) + cbase * 512;

  f32x4 acc[4][4];   // acc[ii(n)][jj(j)]
#pragma unroll
  for (int i = 0; i < 4; ++i)
#pragma unroll
    for (int j = 0; j < 4; ++j) acc[i][j] = (f32x4){0.f, 0.f, 0.f, 0.f};

  // prologue: issue stages 0,1,2 (12 loads/wave in flight)
  K3_STAGE(0)
  K3_STAGE(1)
  K3_STAGE(2)

  // steady state: 13 iters (kk=0..12), each issues stage kk+3 (3..15)
#pragma unroll 1
  for (int kk = 0; kk < 13; ++kk) {
    asm volatile("s_waitcnt vmcnt(8)\n\ts_barrier" ::: "memory");
    K3_STAGE(kk + 3)
    K3_COMPUTE((kk & 3) * 4096)
  }
  // tail: kk=13,14,15 — drain 8 -> 4 -> 0
  asm volatile("s_waitcnt vmcnt(8)\n\ts_barrier" ::: "memory");
  K3_COMPUTE(1 * 4096)
  asm volatile("s_waitcnt vmcnt(4)\n\ts_barrier" ::: "memory");
  K3_COMPUTE(2 * 4096)
  asm volatile("s_waitcnt vmcnt(0)\n\ts_barrier" ::: "memory");

  // prime x-prefetch for ii=0,1 (8 float4) so HBM latency hides under the
  // final 16 MFMAs, then compute last stage.
  int n0b = nt * 128 + wn2 + qd * 4;
  float4 xp0[4], xp1[4];
#pragma unroll
  for (int jj = 0; jj < 4; ++jj) {
    size_t rb = ((size_t)(d * CC + jt * 128 + wj + jj * 16 + fr)) * NN;
    xp0[jj] = *(const float4*)(x + rb + n0b);
    xp1[jj] = *(const float4*)(x + rb + n0b + 16);
  }
  K3_COMPUTE(3 * 4096)

  // epilogue: load-before-store rolling, 2 groups in flight.
  float g = gamma[0];
  float4 x2[4], x3[4];
#pragma unroll
  for (int jj = 0; jj < 4; ++jj)
    x2[jj] = *(const float4*)(x + ((size_t)(d * CC + jt * 128 + wj + jj * 16 + fr)) * NN + n0b + 32);
#pragma unroll
  for (int jj = 0; jj < 4; ++jj) {
    size_t idx = ((size_t)(d * CC + jt * 128 + wj + jj * 16 + fr)) * NN + n0b;
    *(float4*)(out + idx) = make_float4(g * acc[0][jj][0] + xp0[jj].x,
                                        g * acc[0][jj][1] + xp0[jj].y,
                                        g * acc[0][jj][2] + xp0[jj].z,
                                        g * acc[0][jj][3] + xp0[jj].w);
  }
#pragma unroll
  for (int jj = 0; jj < 4; ++jj)
    x3[jj] = *(const float4*)(x + ((size_t)(d * CC + jt * 128 + wj + jj * 16 + fr)) * NN + n0b + 48);
#pragma unroll
  for (int jj = 0; jj < 4; ++jj) {
    size_t idx = ((size_t)(d * CC + jt * 128 + wj + jj * 16 + fr)) * NN + n0b + 16;
    *(float4*)(out + idx) = make_float4(g * acc[1][jj][0] + xp1[jj].x,
                                        g * acc[1][jj][1] + xp1[jj].y,
                                        g * acc[1][jj][2] + xp1[jj].z,
                                        g * acc[1][jj][3] + xp1[jj].w);
  }
#pragma unroll
  for (int jj = 0; jj < 4; ++jj) {
    size_t idx = ((size_t)(d * CC + jt * 128 + wj + jj * 16 + fr)) * NN + n0b + 32;
    *(float4*)(out + idx) = make_float4(g * acc[2][jj][0] + x2[jj].x,
                                        g * acc[2][jj][1] + x2[jj].y,
                                        g * acc[2][jj][2] + x2[jj].z,
                                        g * acc[2][jj][3] + x2[jj].w);
  }
#pragma unroll
  for (int jj = 0; jj < 4; ++jj) {
    size_t idx = ((size_t)(d * CC + jt * 128 + wj + jj * 16 + fr)) * NN + n0b + 48;
    *(float4*)(out + idx) = make_float4(g * acc[3][jj][0] + x3[jj].x,
                                        g * acc[3][jj][1] + x3[jj].y,
                                        g * acc[3][jj][2] + x3[jj].z,
                                        g * acc[3][jj][3] + x3[jj].w);
  }
}

// ---------------------------------------------------------------------------
extern "C" void kernel_launch(void* const* d_in, const int* in_sizes, int n_in,
                              void* d_out, int out_size, void* d_ws, size_t ws_size,
                              hipStream_t stream) {
  (void)in_sizes; (void)n_in; (void)out_size;
  const float* x     = (const float*)d_in[0];
  const float* atten = (const float*)d_in[1];
  const float* gamma = (const float*)d_in[2];
  float* out = (float*)d_out;

  char* ws = (char*)d_ws;
  ushort* qh  = (ushort*)(ws);                    // 33554432 B
  ushort* ql  = (ushort*)(ws + 33554432);         // 33554432 B
  ushort* qt  = (ushort*)(ws + 67108864);         // 33554432 B
  ushort* a2t = (ushort*)(ws + 100663296);        // 4194304 B
  float*  Ep  = (float*) (ws + 104857600);        // ns * 8388608 B

  // split-K: 8 if workspace allows (Ep = 67.1 MB), else 4 (proven footprint)
  int ns = (ws_size >= 104857600ULL + 8ULL * 8388608ULL) ? 8 : 4;
  int ksp = NN / ns;
  int nkk = ksp / 32;

  k0_convert<<<dim3(64, 8, 8), 256, 0, stream>>>(x, qh, ql, qt);
  k1_gram   <<<dim3(80 * ns), 256, 0, stream>>>(qh, ql, Ep, ns, nkk, ksp);
  k2_softmax<<<dim3(512), 256, 0, stream>>>(Ep, atten, a2t, ns);
  k3_out    <<<dim3(1024), 256, 0, stream>>>(a2t, qt, x, gamma, out);
}